// Round 1
// baseline (399.561 us; speedup 1.0000x reference)
//
#include <hip/hip_runtime.h>
#include <hip/hip_bf16.h>
#include <math.h>

typedef float f32x4 __attribute__((ext_vector_type(4)));
typedef short bf16x8 __attribute__((ext_vector_type(8)));
typedef short bf16x4 __attribute__((ext_vector_type(4)));

__device__ __forceinline__ short f2bf(float f) {
    unsigned u = __float_as_uint(f);
    unsigned r = (u + 0x7fffu + ((u >> 16) & 1u)) >> 16;
    return (short)r;
}

// ---------------- kernel 0: transpose weights to bf16 Wt[wsel][n][k] = W[k][n]
__global__ void k_wt(const float* __restrict__ Wq, const float* __restrict__ Wk,
                     const float* __restrict__ Wv, short* __restrict__ Wt) {
    int bidx = blockIdx.x;              // 768 = 3 * 256
    int wsel = bidx >> 8, n = bidx & 255, k = threadIdx.x;
    const float* W = (wsel == 0) ? Wq : (wsel == 1) ? Wk : Wv;
    Wt[(wsel * 256 + n) * 256 + k] = f2bf(W[k * 256 + n]);
}

// ---------------- kernel 1: xt[b][p][c] = bf16(x[b][c][p] + pe[c][p])
__global__ __launch_bounds__(256) void k_pe_xt(const float* __restrict__ x,
                                               short* __restrict__ xt) {
    int bid = blockIdx.x;               // 512 = 4 b * 128 pblocks(32)
    int b = bid >> 7;
    int pb = bid & 127;
    __shared__ __align__(16) float tile[256][33];
    __shared__ __align__(16) float pew[128][32];
    __shared__ __align__(16) float peh[128];
    int t = threadIdx.x;
    const float c1 = 0.14391156f;       // ln(10000)/64
    int wbase = (pb & 1) * 32;
    int hpos = pb >> 1;
    // pe tables (only 128c x 32pp + 128c distinct values per WG)
    #pragma unroll
    for (int j = 0; j < 16; ++j) {
        int idx = t + j * 256;          // < 4096
        int c = idx >> 5, pp = idx & 31;
        int i = c >> 1;
        float d = expf(-(float)i * c1);
        float arg = (float)(wbase + pp) * d;
        pew[c][pp] = (c & 1) ? cosf(arg) : sinf(arg);
    }
    if (t < 128) {
        int i = t >> 1;
        float d = expf(-(float)i * c1);
        float arg = (float)hpos * d;
        peh[t] = (t & 1) ? cosf(arg) : sinf(arg);
    }
    int p0 = pb * 32;
    #pragma unroll
    for (int j = 0; j < 32; ++j) {
        int c = j * 8 + (t >> 5);
        int pp = t & 31;
        tile[c][pp] = x[((b * 256 + c) << 12) + p0 + pp];
    }
    __syncthreads();
    int pp = t >> 3, cseg = t & 7;
    int p = p0 + pp;
    short* dst = xt + (((b << 12) + p) << 8) + (cseg << 5);
    #pragma unroll
    for (int j = 0; j < 4; ++j) {
        bf16x8 v;
        #pragma unroll
        for (int e = 0; e < 8; ++e) {
            int c = cseg * 32 + j * 8 + e;
            float pe = (c < 128) ? pew[c][pp] : peh[c - 128];
            v[e] = f2bf(tile[c][pp] + pe);
        }
        ((bf16x8*)dst)[j] = v;
    }
}

// ---------------- kernel 2: projections Q = xt@Wq, K = xt@Wk, V^T
__global__ __launch_bounds__(256) void k_proj(const short* __restrict__ xt,
                                              const short* __restrict__ Wt,
                                              short* __restrict__ Q,
                                              short* __restrict__ K,
                                              short* __restrict__ VT) {
    int id = blockIdx.x;                // 768 = 4b * 32mt * 2nt * 3w
    int wsel = id % 3; id /= 3;
    int nt = id & 1;  id >>= 1;
    int mt = id & 31; int b = id >> 5;
    int t = threadIdx.x, l = t & 63, w = t >> 6;
    int lr = l & 15, lg = l >> 4;
    int m0 = mt * 128 + (w >> 1) * 64;
    int n0 = nt * 128 + (w & 1) * 64;
    const short* wbase = Wt + wsel * 65536;
    f32x4 acc[4][4] = {};
    #pragma unroll
    for (int s = 0; s < 8; ++s) {
        bf16x8 af[4], bw[4];
        #pragma unroll
        for (int ms = 0; ms < 4; ++ms)
            af[ms] = *(const bf16x8*)(xt + ((b << 12) + m0 + ms * 16 + lr) * 256 + s * 32 + lg * 8);
        #pragma unroll
        for (int fn = 0; fn < 4; ++fn)
            bw[fn] = *(const bf16x8*)(wbase + (n0 + fn * 16 + lr) * 256 + s * 32 + lg * 8);
        #pragma unroll
        for (int ms = 0; ms < 4; ++ms)
            #pragma unroll
            for (int fn = 0; fn < 4; ++fn)
                acc[ms][fn] = __builtin_amdgcn_mfma_f32_16x16x32_bf16(af[ms], bw[fn], acc[ms][fn], 0, 0, 0);
    }
    if (wsel < 2) {
        short* dst = (wsel == 0) ? Q : K;
        #pragma unroll
        for (int ms = 0; ms < 4; ++ms)
            #pragma unroll
            for (int fn = 0; fn < 4; ++fn)
                #pragma unroll
                for (int r = 0; r < 4; ++r) {
                    int m = m0 + ms * 16 + lg * 4 + r;
                    int n = n0 + fn * 16 + lr;
                    dst[((b << 12) + m) * 256 + n] = f2bf(acc[ms][fn][r]);
                }
    } else {
        #pragma unroll
        for (int ms = 0; ms < 4; ++ms)
            #pragma unroll
            for (int fn = 0; fn < 4; ++fn) {
                int n = n0 + fn * 16 + lr;
                int m = m0 + ms * 16 + lg * 4;
                bf16x4 v;
                #pragma unroll
                for (int r = 0; r < 4; ++r) v[r] = f2bf(acc[ms][fn][r]);
                *(bf16x4*)(VT + ((b * 256 + n) << 12) + m) = v;
            }
    }
}

// ---------------- kernel 3 (pass A): column stats m[k], 1/l[k] of softmax over q
__global__ __launch_bounds__(512) void k_stats(const short* __restrict__ Qm,
                                               const short* __restrict__ Km,
                                               float* __restrict__ cmax,
                                               float* __restrict__ crw) {
    int bid = blockIdx.x;               // 256 = 4b * 64 kblocks(64)
    int b = bid >> 6, kb = (bid & 63) * 64;
    int t = threadIdx.x, l = t & 63, w = t >> 6;
    int wk = w & 3, wq = w >> 2;        // wave: 16 kcols (wk), q-half (wq)
    int lr = l & 15, lg = l >> 4;
    __shared__ __align__(16) short qlds[64 * 264];
    // persistent K b-frags for this wave's 16 columns
    bf16x8 bk[8];
    const short* Krow = Km + ((b << 12) + kb + wk * 16 + lr) * 256;
    #pragma unroll
    for (int s = 0; s < 8; ++s) bk[s] = *(const bf16x8*)(Krow + s * 32 + lg * 8);
    float mrun = -3.0e38f, lrun = 0.f;
    for (int qt = 0; qt < 4096; qt += 64) {
        #pragma unroll
        for (int i = 0; i < 4; ++i) {
            int u = i * 512 + t;
            int row = u >> 5, colu = u & 31;
            *(bf16x8*)(qlds + row * 264 + colu * 8) =
                *(const bf16x8*)(Qm + ((b << 12) + qt + row) * 256 + colu * 8);
        }
        __syncthreads();
        float vals[8];
        #pragma unroll
        for (int qs = 0; qs < 2; ++qs) {
            f32x4 acc = {};
            #pragma unroll
            for (int s = 0; s < 8; ++s) {
                bf16x8 a = *(const bf16x8*)(qlds + ((wq * 2 + qs) * 16 + lr) * 264 + s * 32 + lg * 8);
                acc = __builtin_amdgcn_mfma_f32_16x16x32_bf16(a, bk[s], acc, 0, 0, 0);
            }
            #pragma unroll
            for (int r = 0; r < 4; ++r) vals[qs * 4 + r] = acc[r] * 0.0625f;
        }
        float tm = vals[0];
        #pragma unroll
        for (int i = 1; i < 8; ++i) tm = fmaxf(tm, vals[i]);
        tm = fmaxf(tm, __shfl_xor(tm, 16));
        tm = fmaxf(tm, __shfl_xor(tm, 32));
        float mnew = fmaxf(mrun, tm);
        float ts = 0.f;
        #pragma unroll
        for (int i = 0; i < 8; ++i) ts += __expf(vals[i] - mnew);
        ts += __shfl_xor(ts, 16);
        ts += __shfl_xor(ts, 32);
        lrun = lrun * __expf(mrun - mnew) + ts;
        mrun = mnew;
        __syncthreads();
    }
    // merge the two q-halves per column via LDS
    float* red = (float*)qlds;
    if (lg == 0) { red[(w * 16 + lr) * 2] = mrun; red[(w * 16 + lr) * 2 + 1] = lrun; }
    __syncthreads();
    if (wq == 0 && lg == 0) {
        int o0 = (wk * 16 + lr) * 2, o1 = ((4 + wk) * 16 + lr) * 2;
        float m0 = red[o0], l0 = red[o0 + 1];
        float m1 = red[o1], l1 = red[o1 + 1];
        float m = fmaxf(m0, m1);
        float lsum = l0 * __expf(m0 - m) + l1 * __expf(m1 - m);
        int kcol = kb + wk * 16 + lr;
        cmax[(b << 12) + kcol] = m;
        crw[(b << 12) + kcol] = 1.0f / lsum;
    }
}

// ---------------- kernel 4 (pass B): out[q][c] = sum_k exp(S-m[k])/l[k] * V[k][c]
__global__ __launch_bounds__(512) void k_attn(const short* __restrict__ Qm,
                                              const short* __restrict__ Km,
                                              const short* __restrict__ VT,
                                              const float* __restrict__ cmax,
                                              const float* __restrict__ crw,
                                              float* __restrict__ out) {
    int bid = blockIdx.x;               // 256 = 4b * 64 qblocks(64)
    int b = bid >> 6, qb = (bid & 63) * 64;
    int t = threadIdx.x, l = t & 63, w = t >> 6;
    int wq = w & 3, wk = w >> 2;        // S phase: q group (16 rows), k half (32 cols)
    int lr = l & 15, lg = l >> 4;
    __shared__ __align__(16) short klds[64 * 264];
    __shared__ __align__(16) short plds[64 * 72];
    // persistent Q a-frags (this wave's 16 q rows)
    bf16x8 aq[8];
    const short* Qrow = Qm + ((b << 12) + qb + wq * 16 + lr) * 256;
    #pragma unroll
    for (int s = 0; s < 8; ++s) aq[s] = *(const bf16x8*)(Qrow + s * 32 + lg * 8);
    f32x4 o[4][2] = {};
    const float* cmb = cmax + (b << 12);
    const float* cwb = crw + (b << 12);
    for (int kc = 0; kc < 4096; kc += 64) {
        // stage K chunk -> padded LDS
        #pragma unroll
        for (int i = 0; i < 4; ++i) {
            int u = i * 512 + t;
            int row = u >> 5, colu = u & 31;
            *(bf16x8*)(klds + row * 264 + colu * 8) =
                *(const bf16x8*)(Km + ((b << 12) + kc + row) * 256 + colu * 8);
        }
        __syncthreads();
        // S tile: this wave's 16 q x 32 k
        f32x4 sacc[2] = {};
        #pragma unroll
        for (int s = 0; s < 8; ++s) {
            #pragma unroll
            for (int fn = 0; fn < 2; ++fn) {
                bf16x8 bkf = *(const bf16x8*)(klds + (wk * 32 + fn * 16 + lr) * 264 + s * 32 + lg * 8);
                sacc[fn] = __builtin_amdgcn_mfma_f32_16x16x32_bf16(aq[s], bkf, sacc[fn], 0, 0, 0);
            }
        }
        // P' = exp(S*scale - m[k]) * (1/l[k]) -> bf16 -> plds
        #pragma unroll
        for (int fn = 0; fn < 2; ++fn) {
            int kcol = wk * 32 + fn * 16 + lr;
            float mk = cmb[kc + kcol], wkk = cwb[kc + kcol];
            #pragma unroll
            for (int r = 0; r < 4; ++r) {
                float pv = __expf(sacc[fn][r] * 0.0625f - mk) * wkk;
                plds[(wq * 16 + lg * 4 + r) * 72 + kcol] = f2bf(pv);
            }
        }
        __syncthreads();
        // PV: this wave owns 32 output channels [w*32, w*32+32)
        #pragma unroll
        for (int kk = 0; kk < 2; ++kk) {
            bf16x8 ap[4];
            #pragma unroll
            for (int qs = 0; qs < 4; ++qs)
                ap[qs] = *(const bf16x8*)(plds + (qs * 16 + lr) * 72 + kk * 32 + lg * 8);
            #pragma unroll
            for (int fc = 0; fc < 2; ++fc) {
                bf16x8 bv = *(const bf16x8*)(VT + ((b * 256 + w * 32 + fc * 16 + lr) << 12) + kc + kk * 32 + lg * 8);
                #pragma unroll
                for (int qs = 0; qs < 4; ++qs)
                    o[qs][fc] = __builtin_amdgcn_mfma_f32_16x16x32_bf16(ap[qs], bv, o[qs][fc], 0, 0, 0);
            }
        }
    }
    // write out[b][c][p] (f32), p-contiguous float4
    #pragma unroll
    for (int qs = 0; qs < 4; ++qs)
        #pragma unroll
        for (int fc = 0; fc < 2; ++fc) {
            int c = w * 32 + fc * 16 + lr;
            int p = qb + qs * 16 + lg * 4;
            *(f32x4*)(out + ((b * 256 + c) << 12) + p) = o[qs][fc];
        }
}

extern "C" void kernel_launch(void* const* d_in, const int* in_sizes, int n_in,
                              void* d_out, int out_size, void* d_ws, size_t ws_size,
                              hipStream_t stream) {
    const float* x  = (const float*)d_in[0];
    const float* Wq = (const float*)d_in[1];
    const float* Wk = (const float*)d_in[2];
    const float* Wv = (const float*)d_in[3];

    char* p = (char*)d_ws;
    short* xt  = (short*)p; p += 4 * 4096 * 256 * 2;   // 8 MB
    short* Wt  = (short*)p; p += 3 * 256 * 256 * 2;    // 384 KB
    short* Qm  = (short*)p; p += 4 * 4096 * 256 * 2;
    short* Km  = (short*)p; p += 4 * 4096 * 256 * 2;
    short* VT  = (short*)p; p += 4 * 4096 * 256 * 2;
    float* cmaxp = (float*)p; p += 4 * 4096 * 4;
    float* crwp  = (float*)p; p += 4 * 4096 * 4;

    float* out = (float*)d_out;

    k_wt   <<<768, 256, 0, stream>>>(Wq, Wk, Wv, Wt);
    k_pe_xt<<<512, 256, 0, stream>>>(x, xt);
    k_proj <<<768, 256, 0, stream>>>(xt, Wt, Qm, Km, VT);
    k_stats<<<256, 512, 0, stream>>>(Qm, Km, cmaxp, crwp);
    k_attn <<<256, 512, 0, stream>>>(Qm, Km, VT, cmaxp, crwp, out);
}

// Round 2
// 256.958 us; speedup vs baseline: 1.5550x; 1.5550x over previous
//
#include <hip/hip_runtime.h>
#include <hip/hip_bf16.h>
#include <math.h>

typedef float f32x4 __attribute__((ext_vector_type(4)));
typedef short bf16x8 __attribute__((ext_vector_type(8)));
typedef short bf16x4 __attribute__((ext_vector_type(4)));

#define AS1 __attribute__((address_space(1)))
#define AS3 __attribute__((address_space(3)))

__device__ __forceinline__ short f2bf(float f) {
    unsigned u = __float_as_uint(f);
    unsigned r = (u + 0x7fffu + ((u >> 16) & 1u)) >> 16;
    return (short)r;
}
__device__ __forceinline__ float bf2f(short s) {
    return __uint_as_float(((unsigned)(unsigned short)s) << 16);
}
__device__ __forceinline__ void gld16(const void* g, void* l) {
    __builtin_amdgcn_global_load_lds((const AS1 unsigned int*)g, (AS3 unsigned int*)l, 16, 0, 0);
}

// ---------------- kernel 0: transpose weights to bf16 Wt[wsel][n][k] = W[k][n]
__global__ void k_wt(const float* __restrict__ Wq, const float* __restrict__ Wk,
                     const float* __restrict__ Wv, short* __restrict__ Wt) {
    int bidx = blockIdx.x;              // 768 = 3 * 256
    int wsel = bidx >> 8, n = bidx & 255, k = threadIdx.x;
    const float* W = (wsel == 0) ? Wq : (wsel == 1) ? Wk : Wv;
    Wt[(wsel * 256 + n) * 256 + k] = f2bf(W[k * 256 + n]);
}

// ---------------- kernel 1: xt[b][p][c] = bf16(x[b][c][p] + pe[c][p])
__global__ __launch_bounds__(256) void k_pe_xt(const float* __restrict__ x,
                                               short* __restrict__ xt) {
    int bid = blockIdx.x;               // 512 = 4 b * 128 pblocks(32)
    int b = bid >> 7;
    int pb = bid & 127;
    __shared__ __align__(16) float tile[256][33];
    __shared__ __align__(16) float pew[128][32];
    __shared__ __align__(16) float peh[128];
    int t = threadIdx.x;
    const float c1 = 0.14391156f;       // ln(10000)/64
    int wbase = (pb & 1) * 32;
    int hpos = pb >> 1;
    #pragma unroll
    for (int j = 0; j < 16; ++j) {
        int idx = t + j * 256;          // < 4096
        int c = idx >> 5, pp = idx & 31;
        int i = c >> 1;
        float d = expf(-(float)i * c1);
        float arg = (float)(wbase + pp) * d;
        pew[c][pp] = (c & 1) ? cosf(arg) : sinf(arg);
    }
    if (t < 128) {
        int i = t >> 1;
        float d = expf(-(float)i * c1);
        float arg = (float)hpos * d;
        peh[t] = (t & 1) ? cosf(arg) : sinf(arg);
    }
    int p0 = pb * 32;
    #pragma unroll
    for (int j = 0; j < 32; ++j) {
        int c = j * 8 + (t >> 5);
        int pp = t & 31;
        tile[c][pp] = x[((b * 256 + c) << 12) + p0 + pp];
    }
    __syncthreads();
    int pp = t >> 3, cseg = t & 7;
    int p = p0 + pp;
    short* dst = xt + (((b << 12) + p) << 8) + (cseg << 5);
    #pragma unroll
    for (int j = 0; j < 4; ++j) {
        bf16x8 v;
        #pragma unroll
        for (int e = 0; e < 8; ++e) {
            int c = cseg * 32 + j * 8 + e;
            float pe = (c < 128) ? pew[c][pp] : peh[c - 128];
            v[e] = f2bf(tile[c][pp] + pe);
        }
        ((bf16x8*)dst)[j] = v;
    }
}

// ---------------- kernel 2: projections Q = xt@Wq, K = xt@Wk, V^T
__global__ __launch_bounds__(256) void k_proj(const short* __restrict__ xt,
                                              const short* __restrict__ Wt,
                                              short* __restrict__ Q,
                                              short* __restrict__ K,
                                              short* __restrict__ VT) {
    int id = blockIdx.x;                // 768 = 4b * 32mt * 2nt * 3w
    int wsel = id % 3; id /= 3;
    int nt = id & 1;  id >>= 1;
    int mt = id & 31; int b = id >> 5;
    int t = threadIdx.x, l = t & 63, w = t >> 6;
    int lr = l & 15, lg = l >> 4;
    int m0 = mt * 128 + (w >> 1) * 64;
    int n0 = nt * 128 + (w & 1) * 64;
    const short* wbase = Wt + wsel * 65536;
    f32x4 acc[4][4] = {};
    #pragma unroll
    for (int s = 0; s < 8; ++s) {
        bf16x8 af[4], bw[4];
        #pragma unroll
        for (int ms = 0; ms < 4; ++ms)
            af[ms] = *(const bf16x8*)(xt + ((b << 12) + m0 + ms * 16 + lr) * 256 + s * 32 + lg * 8);
        #pragma unroll
        for (int fn = 0; fn < 4; ++fn)
            bw[fn] = *(const bf16x8*)(wbase + (n0 + fn * 16 + lr) * 256 + s * 32 + lg * 8);
        #pragma unroll
        for (int ms = 0; ms < 4; ++ms)
            #pragma unroll
            for (int fn = 0; fn < 4; ++fn)
                acc[ms][fn] = __builtin_amdgcn_mfma_f32_16x16x32_bf16(af[ms], bw[fn], acc[ms][fn], 0, 0, 0);
    }
    if (wsel < 2) {
        short* dst = (wsel == 0) ? Q : K;
        #pragma unroll
        for (int ms = 0; ms < 4; ++ms)
            #pragma unroll
            for (int fn = 0; fn < 4; ++fn)
                #pragma unroll
                for (int r = 0; r < 4; ++r) {
                    int m = m0 + ms * 16 + lg * 4 + r;
                    int n = n0 + fn * 16 + lr;
                    dst[((b << 12) + m) * 256 + n] = f2bf(acc[ms][fn][r]);
                }
    } else {
        #pragma unroll
        for (int ms = 0; ms < 4; ++ms)
            #pragma unroll
            for (int fn = 0; fn < 4; ++fn) {
                int n = n0 + fn * 16 + lr;
                int m = m0 + ms * 16 + lg * 4;
                bf16x4 v;
                #pragma unroll
                for (int r = 0; r < 4; ++r) v[r] = f2bf(acc[ms][fn][r]);
                *(bf16x4*)(VT + ((b * 256 + n) << 12) + m) = v;
            }
    }
}

// ================= BIG PATH =================
// k_E: computes S^T tiles C[k][q] = (K Q^T)/16, writes E[q][k] = exp(.) bf16,
// plus per-block column(q-range) partial sums pl[b][qt][k].
__global__ __launch_bounds__(256) void k_E(const short* __restrict__ Qm,
                                           const short* __restrict__ Km,
                                           short* __restrict__ E,
                                           float* __restrict__ pl) {
    int o = blockIdx.x;                 // 4096
    int bid = (o & 7) * 512 + (o >> 3); // XCD swizzle (4096 % 8 == 0)
    int qt = bid & 31, kt = (bid >> 5) & 31, b = bid >> 10;
    int t = threadIdx.x, l = t & 63, w = t >> 6;
    int wk2 = w >> 1, wq2 = w & 1;
    int lr = l & 15, lg = l >> 4;
    int k0 = kt * 128 + wk2 * 64;
    int q0 = qt * 128 + wq2 * 64;
    const short* Kbase = Km + ((b << 12) + k0 + lr) * 256 + lg * 8;
    const short* Qbase = Qm + ((b << 12) + q0 + lr) * 256 + lg * 8;
    f32x4 acc[4][4] = {};
    #pragma unroll
    for (int s = 0; s < 8; ++s) {
        bf16x8 a[4], bq[4];
        #pragma unroll
        for (int mk = 0; mk < 4; ++mk)
            a[mk] = *(const bf16x8*)(Kbase + mk * 4096 + s * 32);
        #pragma unroll
        for (int nq = 0; nq < 4; ++nq)
            bq[nq] = *(const bf16x8*)(Qbase + nq * 4096 + s * 32);
        #pragma unroll
        for (int mk = 0; mk < 4; ++mk)
            #pragma unroll
            for (int nq = 0; nq < 4; ++nq)
                acc[mk][nq] = __builtin_amdgcn_mfma_f32_16x16x32_bf16(a[mk], bq[nq], acc[mk][nq], 0, 0, 0);
    }
    // exp + store E[q][k] (bf16x4 over k) + q-partial sums
    float psum[4][4];                   // [mk][r]
    #pragma unroll
    for (int mk = 0; mk < 4; ++mk) {
        float ps0 = 0.f, ps1 = 0.f, ps2 = 0.f, ps3 = 0.f;
        #pragma unroll
        for (int nq = 0; nq < 4; ++nq) {
            int q = q0 + nq * 16 + lr;
            bf16x4 ev;
            float e0 = __expf(acc[mk][nq][0] * 0.0625f);
            float e1 = __expf(acc[mk][nq][1] * 0.0625f);
            float e2 = __expf(acc[mk][nq][2] * 0.0625f);
            float e3 = __expf(acc[mk][nq][3] * 0.0625f);
            ps0 += e0; ps1 += e1; ps2 += e2; ps3 += e3;
            ev[0] = f2bf(e0); ev[1] = f2bf(e1); ev[2] = f2bf(e2); ev[3] = f2bf(e3);
            *(bf16x4*)(E + ((b << 12) + q) * 4096 + k0 + mk * 16 + lg * 4) = ev;
        }
        psum[mk][0] = ps0; psum[mk][1] = ps1; psum[mk][2] = ps2; psum[mk][3] = ps3;
    }
    // reduce over lr lanes (16 q-cols each)
    #pragma unroll
    for (int mk = 0; mk < 4; ++mk)
        #pragma unroll
        for (int r = 0; r < 4; ++r) {
            float v = psum[mk][r];
            v += __shfl_xor(v, 1);
            v += __shfl_xor(v, 2);
            v += __shfl_xor(v, 4);
            v += __shfl_xor(v, 8);
            psum[mk][r] = v;
        }
    __shared__ float plds[128];
    if (wq2 == 0 && lr == 0) {
        #pragma unroll
        for (int mk = 0; mk < 4; ++mk)
            #pragma unroll
            for (int r = 0; r < 4; ++r)
                plds[wk2 * 64 + mk * 16 + lg * 4 + r] = psum[mk][r];
    }
    __syncthreads();
    if (wq2 == 1 && lr == 0) {
        #pragma unroll
        for (int mk = 0; mk < 4; ++mk)
            #pragma unroll
            for (int r = 0; r < 4; ++r)
                plds[wk2 * 64 + mk * 16 + lg * 4 + r] += psum[mk][r];
    }
    __syncthreads();
    if (t < 128) pl[(b * 32 + qt) * 4096 + kt * 128 + t] = plds[t];
}

// k_lred: rl[b][k] = 1 / sum_qt pl[b][qt][k]
__global__ void k_lred(const float* __restrict__ pl, float* __restrict__ rl) {
    int gid = blockIdx.x * 256 + threadIdx.x;   // 16384
    int b = gid >> 12, k = gid & 4095;
    float s = 0.f;
    #pragma unroll
    for (int qt = 0; qt < 32; ++qt) s += pl[(b * 32 + qt) * 4096 + k];
    rl[gid] = 1.0f / s;
}

// k_vn: Vnt[b][c][k] = VT[b][c][k] * rl[b][k]
__global__ void k_vn(const short* __restrict__ VT, const float* __restrict__ rl,
                     short* __restrict__ Vnt) {
    int gid = blockIdx.x * 256 + threadIdx.x;   // 524288
    int idx8 = gid * 8;
    int b = idx8 >> 20;
    int rem = idx8 & 1048575;
    int k = rem & 4095;
    bf16x8 v = *(const bf16x8*)(VT + idx8);
    const float* rb = rl + (b << 12) + k;
    f32x4 r0 = *(const f32x4*)(rb);
    f32x4 r1 = *(const f32x4*)(rb + 4);
    bf16x8 oo;
    #pragma unroll
    for (int e = 0; e < 8; ++e) {
        float f = bf2f(v[e]);
        float rr = (e < 4) ? r0[e] : r1[e - 4];
        oo[e] = f2bf(f * rr);
    }
    *(bf16x8*)(Vnt + idx8) = oo;
}

// k_pv: out[b][c][q] = sum_k E[q][k] * Vnt[c][k]  (64q x 128c tile, K-loop 64)
__global__ __launch_bounds__(256) void k_pv(const short* __restrict__ E,
                                            const short* __restrict__ Vnt,
                                            float* __restrict__ out) {
    int o = blockIdx.x;                 // 512
    int bid = (o & 7) * 64 + (o >> 3);  // XCD swizzle
    int qt = bid & 63, ct = (bid >> 6) & 1, b = bid >> 7;
    int t = threadIdx.x, l = t & 63, w = t >> 6;
    int wq = w >> 1, wc = w & 1;        // wave: 32 q x 64 c
    int lr = l & 15, lg = l >> 4;
    int q0 = qt * 64, c0 = ct * 128;
    __shared__ __align__(16) short Ea[64 * 64];
    __shared__ __align__(16) short Va[128 * 64];
    f32x4 acc[2][4] = {};
    for (int kc = 0; kc < 4096; kc += 64) {
        // stage E tile rows=q [64][64], XOR-swizzled via pre-swizzled source
        #pragma unroll
        for (int j = 0; j < 2; ++j) {
            int ii = j * 4 + w;
            int row = ii * 8 + (l >> 3);
            int slot = (l & 7) ^ (row & 7);
            gld16(E + ((b << 12) + q0 + row) * 4096 + kc + slot * 8, Ea + ii * 512);
        }
        // stage Vnt tile rows=c [128][64]
        #pragma unroll
        for (int j = 0; j < 4; ++j) {
            int ii = j * 4 + w;
            int row = ii * 8 + (l >> 3);
            int slot = (l & 7) ^ (row & 7);
            gld16(Vnt + ((b << 8) + c0 + row) * 4096 + kc + slot * 8, Va + ii * 512);
        }
        __syncthreads();
        bf16x8 Af[2][2], Bf[4][2];
        #pragma unroll
        for (int s = 0; s < 2; ++s) {
            #pragma unroll
            for (int mq = 0; mq < 2; ++mq) {
                int row = wq * 32 + mq * 16 + lr;
                int slot = (s * 4 + lg) ^ (row & 7);
                Af[mq][s] = *(const bf16x8*)(Ea + row * 64 + slot * 8);
            }
            #pragma unroll
            for (int nc = 0; nc < 4; ++nc) {
                int row = wc * 64 + nc * 16 + lr;
                int slot = (s * 4 + lg) ^ (row & 7);
                Bf[nc][s] = *(const bf16x8*)(Va + row * 64 + slot * 8);
            }
        }
        #pragma unroll
        for (int s = 0; s < 2; ++s)
            #pragma unroll
            for (int mq = 0; mq < 2; ++mq)
                #pragma unroll
                for (int nc = 0; nc < 4; ++nc)
                    acc[mq][nc] = __builtin_amdgcn_mfma_f32_16x16x32_bf16(Af[mq][s], Bf[nc][s], acc[mq][nc], 0, 0, 0);
        __syncthreads();
    }
    #pragma unroll
    for (int mq = 0; mq < 2; ++mq)
        #pragma unroll
        for (int nc = 0; nc < 4; ++nc) {
            int c = c0 + wc * 64 + nc * 16 + lr;
            int q = q0 + wq * 32 + mq * 16 + lg * 4;
            *(f32x4*)(out + ((b << 8) + c) * 4096 + q) = acc[mq][nc];
        }
}

// ================= FALLBACK PATH (round-1, passing) =================
__global__ __launch_bounds__(512) void k_stats(const short* __restrict__ Qm,
                                               const short* __restrict__ Km,
                                               float* __restrict__ cmax,
                                               float* __restrict__ crw) {
    int bid = blockIdx.x;
    int b = bid >> 6, kb = (bid & 63) * 64;
    int t = threadIdx.x, l = t & 63, w = t >> 6;
    int wk = w & 3, wq = w >> 2;
    int lr = l & 15, lg = l >> 4;
    __shared__ __align__(16) short qlds[64 * 264];
    bf16x8 bk[8];
    const short* Krow = Km + ((b << 12) + kb + wk * 16 + lr) * 256;
    #pragma unroll
    for (int s = 0; s < 8; ++s) bk[s] = *(const bf16x8*)(Krow + s * 32 + lg * 8);
    float mrun = -3.0e38f, lrun = 0.f;
    for (int qt = 0; qt < 4096; qt += 64) {
        #pragma unroll
        for (int i = 0; i < 4; ++i) {
            int u = i * 512 + t;
            int row = u >> 5, colu = u & 31;
            *(bf16x8*)(qlds + row * 264 + colu * 8) =
                *(const bf16x8*)(Qm + ((b << 12) + qt + row) * 256 + colu * 8);
        }
        __syncthreads();
        float vals[8];
        #pragma unroll
        for (int qs = 0; qs < 2; ++qs) {
            f32x4 acc = {};
            #pragma unroll
            for (int s = 0; s < 8; ++s) {
                bf16x8 a = *(const bf16x8*)(qlds + ((wq * 2 + qs) * 16 + lr) * 264 + s * 32 + lg * 8);
                acc = __builtin_amdgcn_mfma_f32_16x16x32_bf16(a, bk[s], acc, 0, 0, 0);
            }
            #pragma unroll
            for (int r = 0; r < 4; ++r) vals[qs * 4 + r] = acc[r] * 0.0625f;
        }
        float tm = vals[0];
        #pragma unroll
        for (int i = 1; i < 8; ++i) tm = fmaxf(tm, vals[i]);
        tm = fmaxf(tm, __shfl_xor(tm, 16));
        tm = fmaxf(tm, __shfl_xor(tm, 32));
        float mnew = fmaxf(mrun, tm);
        float ts = 0.f;
        #pragma unroll
        for (int i = 0; i < 8; ++i) ts += __expf(vals[i] - mnew);
        ts += __shfl_xor(ts, 16);
        ts += __shfl_xor(ts, 32);
        lrun = lrun * __expf(mrun - mnew) + ts;
        mrun = mnew;
        __syncthreads();
    }
    float* red = (float*)qlds;
    if (lg == 0) { red[(w * 16 + lr) * 2] = mrun; red[(w * 16 + lr) * 2 + 1] = lrun; }
    __syncthreads();
    if (wq == 0 && lg == 0) {
        int o0 = (wk * 16 + lr) * 2, o1 = ((4 + wk) * 16 + lr) * 2;
        float m0 = red[o0], l0 = red[o0 + 1];
        float m1 = red[o1], l1 = red[o1 + 1];
        float m = fmaxf(m0, m1);
        float lsum = l0 * __expf(m0 - m) + l1 * __expf(m1 - m);
        int kcol = kb + wk * 16 + lr;
        cmax[(b << 12) + kcol] = m;
        crw[(b << 12) + kcol] = 1.0f / lsum;
    }
}

__global__ __launch_bounds__(512) void k_attn(const short* __restrict__ Qm,
                                              const short* __restrict__ Km,
                                              const short* __restrict__ VT,
                                              const float* __restrict__ cmax,
                                              const float* __restrict__ crw,
                                              float* __restrict__ out) {
    int bid = blockIdx.x;
    int b = bid >> 6, qb = (bid & 63) * 64;
    int t = threadIdx.x, l = t & 63, w = t >> 6;
    int wq = w & 3, wk = w >> 2;
    int lr = l & 15, lg = l >> 4;
    __shared__ __align__(16) short klds[64 * 264];
    __shared__ __align__(16) short plds[64 * 72];
    bf16x8 aq[8];
    const short* Qrow = Qm + ((b << 12) + qb + wq * 16 + lr) * 256;
    #pragma unroll
    for (int s = 0; s < 8; ++s) aq[s] = *(const bf16x8*)(Qrow + s * 32 + lg * 8);
    f32x4 oacc[4][2] = {};
    const float* cmb = cmax + (b << 12);
    const float* cwb = crw + (b << 12);
    for (int kc = 0; kc < 4096; kc += 64) {
        #pragma unroll
        for (int i = 0; i < 4; ++i) {
            int u = i * 512 + t;
            int row = u >> 5, colu = u & 31;
            *(bf16x8*)(klds + row * 264 + colu * 8) =
                *(const bf16x8*)(Km + ((b << 12) + kc + row) * 256 + colu * 8);
        }
        __syncthreads();
        f32x4 sacc[2] = {};
        #pragma unroll
        for (int s = 0; s < 8; ++s) {
            #pragma unroll
            for (int fn = 0; fn < 2; ++fn) {
                bf16x8 bkf = *(const bf16x8*)(klds + (wk * 32 + fn * 16 + lr) * 264 + s * 32 + lg * 8);
                sacc[fn] = __builtin_amdgcn_mfma_f32_16x16x32_bf16(aq[s], bkf, sacc[fn], 0, 0, 0);
            }
        }
        #pragma unroll
        for (int fn = 0; fn < 2; ++fn) {
            int kcol = wk * 32 + fn * 16 + lr;
            float mk = cmb[kc + kcol], wkk = cwb[kc + kcol];
            #pragma unroll
            for (int r = 0; r < 4; ++r) {
                float pv = __expf(sacc[fn][r] * 0.0625f - mk) * wkk;
                plds[(wq * 16 + lg * 4 + r) * 72 + kcol] = f2bf(pv);
            }
        }
        __syncthreads();
        #pragma unroll
        for (int kk = 0; kk < 2; ++kk) {
            bf16x8 ap[4];
            #pragma unroll
            for (int qs = 0; qs < 4; ++qs)
                ap[qs] = *(const bf16x8*)(plds + (qs * 16 + lr) * 72 + kk * 32 + lg * 8);
            #pragma unroll
            for (int fc = 0; fc < 2; ++fc) {
                bf16x8 bv = *(const bf16x8*)(VT + ((b * 256 + w * 32 + fc * 16 + lr) << 12) + kc + kk * 32 + lg * 8);
                #pragma unroll
                for (int qs = 0; qs < 4; ++qs)
                    oacc[qs][fc] = __builtin_amdgcn_mfma_f32_16x16x32_bf16(ap[qs], bv, oacc[qs][fc], 0, 0, 0);
            }
        }
    }
    #pragma unroll
    for (int qs = 0; qs < 4; ++qs)
        #pragma unroll
        for (int fc = 0; fc < 2; ++fc) {
            int c = w * 32 + fc * 16 + lr;
            int p = qb + qs * 16 + lg * 4;
            *(f32x4*)(out + ((b * 256 + c) << 12) + p) = oacc[qs][fc];
        }
}

extern "C" void kernel_launch(void* const* d_in, const int* in_sizes, int n_in,
                              void* d_out, int out_size, void* d_ws, size_t ws_size,
                              hipStream_t stream) {
    const float* x  = (const float*)d_in[0];
    const float* Wq = (const float*)d_in[1];
    const float* Wk = (const float*)d_in[2];
    const float* Wv = (const float*)d_in[3];

    char* p = (char*)d_ws;
    short* xt  = (short*)p; p += 4 * 4096 * 256 * 2;   // 8 MB
    short* Wt  = (short*)p; p += 3 * 256 * 256 * 2;    // 384 KB
    short* Qm  = (short*)p; p += 4 * 4096 * 256 * 2;
    short* Km  = (short*)p; p += 4 * 4096 * 256 * 2;
    short* VT  = (short*)p; p += 4 * 4096 * 256 * 2;

    float* out = (float*)d_out;

    const size_t NEED_BIG = 178716672ULL;

    k_wt   <<<768, 256, 0, stream>>>(Wq, Wk, Wv, Wt);
    k_pe_xt<<<512, 256, 0, stream>>>(x, xt);
    k_proj <<<768, 256, 0, stream>>>(xt, Wt, Qm, Km, VT);

    if (ws_size >= NEED_BIG) {
        short* E   = (short*)p; p += (size_t)4 * 4096 * 4096 * 2;  // 134.2 MB
        float* pl  = (float*)p; p += 4 * 32 * 4096 * 4;            // 2 MB
        float* rl  = (float*)p; p += 4 * 4096 * 4;                 // 64 KB
        short* Vnt = (short*)p; p += 4 * 4096 * 256 * 2;           // 8 MB
        k_E   <<<4096, 256, 0, stream>>>(Qm, Km, E, pl);
        k_lred<<<64,   256, 0, stream>>>(pl, rl);
        k_vn  <<<2048, 256, 0, stream>>>(VT, rl, Vnt);
        k_pv  <<<512,  256, 0, stream>>>(E, Vnt, out);
    } else {
        float* cmaxp = (float*)p; p += 4 * 4096 * 4;
        float* crwp  = (float*)p; p += 4 * 4096 * 4;
        k_stats<<<256, 512, 0, stream>>>(Qm, Km, cmaxp, crwp);
        k_attn <<<256, 512, 0, stream>>>(Qm, Km, VT, cmaxp, crwp, out);
    }
}

// Round 3
// 187.507 us; speedup vs baseline: 2.1309x; 1.3704x over previous
//
#include <hip/hip_runtime.h>
#include <hip/hip_bf16.h>
#include <math.h>

typedef float f32x4 __attribute__((ext_vector_type(4)));
typedef short bf16x8 __attribute__((ext_vector_type(8)));
typedef short bf16x4 __attribute__((ext_vector_type(4)));

#define AS1 __attribute__((address_space(1)))
#define AS3 __attribute__((address_space(3)))

__device__ __forceinline__ short f2bf(float f) {
    unsigned u = __float_as_uint(f);
    unsigned r = (u + 0x7fffu + ((u >> 16) & 1u)) >> 16;
    return (short)r;
}
__device__ __forceinline__ float bf2f(short s) {
    return __uint_as_float(((unsigned)(unsigned short)s) << 16);
}
__device__ __forceinline__ void gld16(const void* g, void* l) {
    __builtin_amdgcn_global_load_lds((const AS1 unsigned int*)g, (AS3 unsigned int*)l, 16, 0, 0);
}

// stage a [128][64]-short tile (global row stride 256 shorts) into linear LDS
// with XOR-swizzled SOURCE (slot ^= row&7) so reads use swizzled addressing.
__device__ __forceinline__ void stage128x64(const short* __restrict__ g,
                                            short* lds, int t) {
    int w = t >> 6, l = t & 63;
    #pragma unroll
    for (int j = 0; j < 4; ++j) {
        int ii = j * 4 + w;
        int row = ii * 8 + (l >> 3);
        int slot = (l & 7) ^ (row & 7);
        gld16(g + row * 256 + slot * 8, lds + ii * 512);
    }
}

// ---------------- kernel 0: transpose weights to bf16 Wt[wsel][n][k] = W[k][n]
__global__ void k_wt(const float* __restrict__ Wq, const float* __restrict__ Wk,
                     const float* __restrict__ Wv, short* __restrict__ Wt) {
    int bidx = blockIdx.x;              // 768 = 3 * 256
    int wsel = bidx >> 8, n = bidx & 255, k = threadIdx.x;
    const float* W = (wsel == 0) ? Wq : (wsel == 1) ? Wk : Wv;
    Wt[(wsel * 256 + n) * 256 + k] = f2bf(W[k * 256 + n]);
}

// ---------------- kernel 1: xt[b][p][c] = bf16(x[b][c][p] + pe[c][p])
__global__ __launch_bounds__(256) void k_pe_xt(const float* __restrict__ x,
                                               short* __restrict__ xt) {
    int bid = blockIdx.x;               // 512 = 4 b * 128 pblocks(32)
    int b = bid >> 7;
    int pb = bid & 127;
    __shared__ __align__(16) float tile[256][33];
    __shared__ __align__(16) float pew[128][32];
    __shared__ __align__(16) float peh[128];
    int t = threadIdx.x;
    const float c1 = 0.14391156f;       // ln(10000)/64
    int wbase = (pb & 1) * 32;
    int hpos = pb >> 1;
    #pragma unroll
    for (int j = 0; j < 16; ++j) {
        int idx = t + j * 256;          // < 4096
        int c = idx >> 5, pp = idx & 31;
        int i = c >> 1;
        float d = expf(-(float)i * c1);
        float arg = (float)(wbase + pp) * d;
        pew[c][pp] = (c & 1) ? cosf(arg) : sinf(arg);
    }
    if (t < 128) {
        int i = t >> 1;
        float d = expf(-(float)i * c1);
        float arg = (float)hpos * d;
        peh[t] = (t & 1) ? cosf(arg) : sinf(arg);
    }
    int p0 = pb * 32;
    #pragma unroll
    for (int j = 0; j < 32; ++j) {
        int c = j * 8 + (t >> 5);
        int pp = t & 31;
        tile[c][pp] = x[((b * 256 + c) << 12) + p0 + pp];
    }
    __syncthreads();
    int pp = t >> 3, cseg = t & 7;
    int p = p0 + pp;
    short* dst = xt + (((b << 12) + p) << 8) + (cseg << 5);
    #pragma unroll
    for (int j = 0; j < 4; ++j) {
        bf16x8 v;
        #pragma unroll
        for (int e = 0; e < 8; ++e) {
            int c = cseg * 32 + j * 8 + e;
            float pe = (c < 128) ? pew[c][pp] : peh[c - 128];
            v[e] = f2bf(tile[c][pp] + pe);
        }
        ((bf16x8*)dst)[j] = v;
    }
}

// ---------------- kernel 2: projections Q = xt@Wq, K = xt@Wk, V^T
__global__ __launch_bounds__(256) void k_proj(const short* __restrict__ xt,
                                              const short* __restrict__ Wt,
                                              short* __restrict__ Q,
                                              short* __restrict__ K,
                                              short* __restrict__ VT) {
    int id = blockIdx.x;                // 768 = 4b * 32mt * 2nt * 3w
    int wsel = id % 3; id /= 3;
    int nt = id & 1;  id >>= 1;
    int mt = id & 31; int b = id >> 5;
    int t = threadIdx.x, l = t & 63, w = t >> 6;
    int lr = l & 15, lg = l >> 4;
    int m0 = mt * 128 + (w >> 1) * 64;
    int n0 = nt * 128 + (w & 1) * 64;
    const short* wbase = Wt + wsel * 65536;
    f32x4 acc[4][4] = {};
    #pragma unroll
    for (int s = 0; s < 8; ++s) {
        bf16x8 af[4], bw[4];
        #pragma unroll
        for (int ms = 0; ms < 4; ++ms)
            af[ms] = *(const bf16x8*)(xt + ((b << 12) + m0 + ms * 16 + lr) * 256 + s * 32 + lg * 8);
        #pragma unroll
        for (int fn = 0; fn < 4; ++fn)
            bw[fn] = *(const bf16x8*)(wbase + (n0 + fn * 16 + lr) * 256 + s * 32 + lg * 8);
        #pragma unroll
        for (int ms = 0; ms < 4; ++ms)
            #pragma unroll
            for (int fn = 0; fn < 4; ++fn)
                acc[ms][fn] = __builtin_amdgcn_mfma_f32_16x16x32_bf16(af[ms], bw[fn], acc[ms][fn], 0, 0, 0);
    }
    if (wsel < 2) {
        short* dst = (wsel == 0) ? Q : K;
        #pragma unroll
        for (int ms = 0; ms < 4; ++ms)
            #pragma unroll
            for (int fn = 0; fn < 4; ++fn)
                #pragma unroll
                for (int r = 0; r < 4; ++r) {
                    int m = m0 + ms * 16 + lg * 4 + r;
                    int n = n0 + fn * 16 + lr;
                    dst[((b << 12) + m) * 256 + n] = f2bf(acc[ms][fn][r]);
                }
    } else {
        #pragma unroll
        for (int ms = 0; ms < 4; ++ms)
            #pragma unroll
            for (int fn = 0; fn < 4; ++fn) {
                int n = n0 + fn * 16 + lr;
                int m = m0 + ms * 16 + lg * 4;
                bf16x4 v;
                #pragma unroll
                for (int r = 0; r < 4; ++r) v[r] = f2bf(acc[ms][fn][r]);
                *(bf16x4*)(VT + ((b * 256 + n) << 12) + m) = v;
            }
    }
}

// ---------------- k_E v2: m97-style LDS-staged GEMM, fused exp + column partials.
// C[k][q] = (K Q^T)/16 per 128x128 tile; E[q][k] = exp(.) bf16; pl[b][qt][k] partial sums over q.
__global__ __launch_bounds__(256) void k_E(const short* __restrict__ Qm,
                                           const short* __restrict__ Km,
                                           short* __restrict__ E,
                                           float* __restrict__ pl) {
    int o = blockIdx.x;                 // 4096
    int bid = (o & 7) * 512 + (o >> 3); // XCD swizzle (4096 % 8 == 0)
    int qt = bid & 31, kt = (bid >> 5) & 31, b = bid >> 10;
    int t = threadIdx.x, l = t & 63;
    int w = t >> 6;
    int wr = w >> 1, wc = w & 1;        // wave sub-tile: 64k x 64q
    int lr = l & 15, lg = l >> 4;
    __shared__ __align__(16) short Ka[2][128 * 64];
    __shared__ __align__(16) short Qa[2][128 * 64];
    __shared__ float plds[128];
    const short* Kg = Km + (((size_t)b << 12) + kt * 128) * 256;
    const short* Qg = Qm + (((size_t)b << 12) + qt * 128) * 256;
    f32x4 acc[4][4] = {};

    stage128x64(Kg, Ka[0], t);
    stage128x64(Qg, Qa[0], t);
    __syncthreads();
    #pragma unroll
    for (int ks = 0; ks < 4; ++ks) {
        if (ks < 3) {
            stage128x64(Kg + (ks + 1) * 64, Ka[(ks + 1) & 1], t);
            stage128x64(Qg + (ks + 1) * 64, Qa[(ks + 1) & 1], t);
        }
        const short* KL = Ka[ks & 1];
        const short* QL = Qa[ks & 1];
        #pragma unroll
        for (int s = 0; s < 2; ++s) {
            bf16x8 a[4], bq[4];
            #pragma unroll
            for (int mk = 0; mk < 4; ++mk) {
                int row = wr * 64 + mk * 16 + lr;
                a[mk] = *(const bf16x8*)(KL + row * 64 + (((s * 4 + lg) ^ (row & 7)) << 3));
            }
            #pragma unroll
            for (int nq = 0; nq < 4; ++nq) {
                int row = wc * 64 + nq * 16 + lr;
                bq[nq] = *(const bf16x8*)(QL + row * 64 + (((s * 4 + lg) ^ (row & 7)) << 3));
            }
            #pragma unroll
            for (int mk = 0; mk < 4; ++mk)
                #pragma unroll
                for (int nq = 0; nq < 4; ++nq)
                    acc[mk][nq] = __builtin_amdgcn_mfma_f32_16x16x32_bf16(a[mk], bq[nq], acc[mk][nq], 0, 0, 0);
        }
        __syncthreads();
    }

    // epilogue: exp, store E, column (q) partial sums
    int k0 = kt * 128 + wr * 64;
    int q0 = qt * 128 + wc * 64;
    float psum[4][4];                   // [mk][r]
    #pragma unroll
    for (int mk = 0; mk < 4; ++mk) {
        float ps0 = 0.f, ps1 = 0.f, ps2 = 0.f, ps3 = 0.f;
        #pragma unroll
        for (int nq = 0; nq < 4; ++nq) {
            int q = q0 + nq * 16 + lr;
            bf16x4 ev;
            float e0 = __expf(acc[mk][nq][0] * 0.0625f);
            float e1 = __expf(acc[mk][nq][1] * 0.0625f);
            float e2 = __expf(acc[mk][nq][2] * 0.0625f);
            float e3 = __expf(acc[mk][nq][3] * 0.0625f);
            ps0 += e0; ps1 += e1; ps2 += e2; ps3 += e3;
            ev[0] = f2bf(e0); ev[1] = f2bf(e1); ev[2] = f2bf(e2); ev[3] = f2bf(e3);
            *(bf16x4*)(E + (((size_t)b << 12) + q) * 4096 + k0 + mk * 16 + lg * 4) = ev;
        }
        psum[mk][0] = ps0; psum[mk][1] = ps1; psum[mk][2] = ps2; psum[mk][3] = ps3;
    }
    #pragma unroll
    for (int mk = 0; mk < 4; ++mk)
        #pragma unroll
        for (int r = 0; r < 4; ++r) {
            float v = psum[mk][r];
            v += __shfl_xor(v, 1);
            v += __shfl_xor(v, 2);
            v += __shfl_xor(v, 4);
            v += __shfl_xor(v, 8);
            psum[mk][r] = v;
        }
    if (wc == 0 && lr == 0) {
        #pragma unroll
        for (int mk = 0; mk < 4; ++mk)
            #pragma unroll
            for (int r = 0; r < 4; ++r)
                plds[wr * 64 + mk * 16 + lg * 4 + r] = psum[mk][r];
    }
    __syncthreads();
    if (wc == 1 && lr == 0) {
        #pragma unroll
        for (int mk = 0; mk < 4; ++mk)
            #pragma unroll
            for (int r = 0; r < 4; ++r)
                plds[wr * 64 + mk * 16 + lg * 4 + r] += psum[mk][r];
    }
    __syncthreads();
    if (t < 128) pl[(b * 32 + qt) * 4096 + kt * 128 + t] = plds[t];
}

// k_lred: rl[b][k] = 1 / sum_qt pl[b][qt][k]
__global__ void k_lred(const float* __restrict__ pl, float* __restrict__ rl) {
    int gid = blockIdx.x * 256 + threadIdx.x;   // 16384
    float s = 0.f;
    int b = gid >> 12, k = gid & 4095;
    #pragma unroll
    for (int qt = 0; qt < 32; ++qt) s += pl[(b * 32 + qt) * 4096 + k];
    rl[gid] = 1.0f / s;
}

// k_vn: Vnt[b][c][k] = VT[b][c][k] * rl[b][k]
__global__ void k_vn(const short* __restrict__ VT, const float* __restrict__ rl,
                     short* __restrict__ Vnt) {
    int gid = blockIdx.x * 256 + threadIdx.x;   // 524288
    int idx8 = gid * 8;
    int b = idx8 >> 20;
    int rem = idx8 & 1048575;
    int k = rem & 4095;
    bf16x8 v = *(const bf16x8*)(VT + idx8);
    const float* rb = rl + (b << 12) + k;
    f32x4 r0 = *(const f32x4*)(rb);
    f32x4 r1 = *(const f32x4*)(rb + 4);
    bf16x8 oo;
    #pragma unroll
    for (int e = 0; e < 8; ++e) {
        float f = bf2f(v[e]);
        float rr = (e < 4) ? r0[e] : r1[e - 4];
        oo[e] = f2bf(f * rr);
    }
    *(bf16x8*)(Vnt + idx8) = oo;
}

// k_pv: out[b][c][q] = sum_k E[q][k] * Vnt[c][k]  (64q x 128c tile, K-loop 64)
__global__ __launch_bounds__(256) void k_pv(const short* __restrict__ E,
                                            const short* __restrict__ Vnt,
                                            float* __restrict__ out) {
    int o = blockIdx.x;                 // 512
    int bid = (o & 7) * 64 + (o >> 3);  // XCD swizzle
    int qt = bid & 63, ct = (bid >> 6) & 1, b = bid >> 7;
    int t = threadIdx.x, l = t & 63, w = t >> 6;
    int wq = w >> 1, wc = w & 1;        // wave: 32 q x 64 c
    int lr = l & 15, lg = l >> 4;
    int q0 = qt * 64, c0 = ct * 128;
    __shared__ __align__(16) short Ea[64 * 64];
    __shared__ __align__(16) short Va[128 * 64];
    f32x4 acc[2][4] = {};
    for (int kc = 0; kc < 4096; kc += 64) {
        #pragma unroll
        for (int j = 0; j < 2; ++j) {
            int ii = j * 4 + w;
            int row = ii * 8 + (l >> 3);
            int slot = (l & 7) ^ (row & 7);
            gld16(E + (((size_t)b << 12) + q0 + row) * 4096 + kc + slot * 8, Ea + ii * 512);
        }
        #pragma unroll
        for (int j = 0; j < 4; ++j) {
            int ii = j * 4 + w;
            int row = ii * 8 + (l >> 3);
            int slot = (l & 7) ^ (row & 7);
            gld16(Vnt + (((size_t)b << 8) + c0 + row) * 4096 + kc + slot * 8, Va + ii * 512);
        }
        __syncthreads();
        bf16x8 Af[2][2], Bf[4][2];
        #pragma unroll
        for (int s = 0; s < 2; ++s) {
            #pragma unroll
            for (int mq = 0; mq < 2; ++mq) {
                int row = wq * 32 + mq * 16 + lr;
                int slot = (s * 4 + lg) ^ (row & 7);
                Af[mq][s] = *(const bf16x8*)(Ea + row * 64 + slot * 8);
            }
            #pragma unroll
            for (int nc = 0; nc < 4; ++nc) {
                int row = wc * 64 + nc * 16 + lr;
                int slot = (s * 4 + lg) ^ (row & 7);
                Bf[nc][s] = *(const bf16x8*)(Va + row * 64 + slot * 8);
            }
        }
        #pragma unroll
        for (int s = 0; s < 2; ++s)
            #pragma unroll
            for (int mq = 0; mq < 2; ++mq)
                #pragma unroll
                for (int nc = 0; nc < 4; ++nc)
                    acc[mq][nc] = __builtin_amdgcn_mfma_f32_16x16x32_bf16(Af[mq][s], Bf[nc][s], acc[mq][nc], 0, 0, 0);
        __syncthreads();
    }
    #pragma unroll
    for (int mq = 0; mq < 2; ++mq)
        #pragma unroll
        for (int nc = 0; nc < 4; ++nc) {
            int c = c0 + wc * 64 + nc * 16 + lr;
            int q = q0 + wq * 32 + mq * 16 + lg * 4;
            *(f32x4*)(out + (((size_t)b << 8) + c) * 4096 + q) = acc[mq][nc];
        }
}

extern "C" void kernel_launch(void* const* d_in, const int* in_sizes, int n_in,
                              void* d_out, int out_size, void* d_ws, size_t ws_size,
                              hipStream_t stream) {
    const float* x  = (const float*)d_in[0];
    const float* Wq = (const float*)d_in[1];
    const float* Wk = (const float*)d_in[2];
    const float* Wv = (const float*)d_in[3];

    char* p = (char*)d_ws;
    short* xt  = (short*)p; p += 4 * 4096 * 256 * 2;   // 8 MB
    short* Wt  = (short*)p; p += 3 * 256 * 256 * 2;    // 384 KB
    short* Qm  = (short*)p; p += 4 * 4096 * 256 * 2;
    short* Km  = (short*)p; p += 4 * 4096 * 256 * 2;
    short* VT  = (short*)p; p += 4 * 4096 * 256 * 2;
    short* E   = (short*)p; p += (size_t)4 * 4096 * 4096 * 2;  // 134.2 MB
    float* pl  = (float*)p; p += 4 * 32 * 4096 * 4;            // 2 MB
    float* rl  = (float*)p; p += 4 * 4096 * 4;                 // 64 KB
    short* Vnt = (short*)p; p += 4 * 4096 * 256 * 2;           // 8 MB

    float* out = (float*)d_out;

    k_wt   <<<768, 256, 0, stream>>>(Wq, Wk, Wv, Wt);
    k_pe_xt<<<512, 256, 0, stream>>>(x, xt);
    k_proj <<<768, 256, 0, stream>>>(xt, Wt, Qm, Km, VT);
    k_E    <<<4096, 256, 0, stream>>>(Qm, Km, E, pl);
    k_lred <<<64,   256, 0, stream>>>(pl, rl);
    k_vn   <<<2048, 256, 0, stream>>>(VT, rl, Vnt);
    k_pv   <<<512,  256, 0, stream>>>(E, Vnt, out);
}